// Round 11
// baseline (563.718 us; speedup 1.0000x reference)
//
#include <hip/hip_runtime.h>
#include <hip/hip_cooperative_groups.h>

namespace cg = cooperative_groups;

// Problem constants (fixed by the reference's setup_inputs)
#define C_DIM 64
#define P_DIM 16
#define K_DIM 9
#define ZROW 10              // padded Zb row (ushorts) per (n,p): 20 B
#define ZNODE (P_DIM * ZROW) // 160 ushorts = 320 B per node
#define NT 10                // n-tiles (permuted 160-slot output layout)
#define WELEM (160 * C_DIM)  // ushorts per W' table (10240)
#define EILP 8
#define INV2S 0.35355339059327373f  // 1/(2*sqrt(2))

typedef __attribute__((ext_vector_type(8))) short short8v;  // 8 bf16 (4 VGPRs)
typedef __attribute__((ext_vector_type(4))) float f32x4;    // MFMA accumulator
typedef uint uint4a __attribute__((ext_vector_type(4), aligned(4)));

__device__ __forceinline__ ushort f2bf(float f) {
    uint u = __builtin_bit_cast(uint, f);
    return (ushort)((u + 0x7FFFu + ((u >> 16) & 1u)) >> 16);   // RNE
}
__device__ __forceinline__ float bf2f(ushort h) {
    return __builtin_bit_cast(float, ((uint)h) << 16);
}

// ---------------------------------------------------------------------------
// Phase 0: permuted W' -> global bf16 hi/lo tables (row j = W[(j/10)*9+j%10],
// zeros at j%10==9), pose -> packed bf16, bias-init of out.
// ---------------------------------------------------------------------------
template <bool USEBF>
__device__ __forceinline__ void do_prep(int gt, int G,
                                        const float* __restrict__ W,
                                        const float* __restrict__ pose,
                                        const float* __restrict__ bias,
                                        float* __restrict__ out,
                                        ushort* __restrict__ Whi,
                                        ushort* __restrict__ Wlo,
                                        uint* __restrict__ pose_bf, int N) {
    if (gt < WELEM / 2) {
        const int j  = gt >> 5;          // W' row (0..159)
        const int k2 = gt & 31;          // float2 index within row
        const int p  = j / 10;
        const int k  = j - p * 10;
        float2 w2 = make_float2(0.0f, 0.0f);
        if (k < 9) w2 = ((const float2*)W)[(p * 9 + k) * (C_DIM / 2) + k2];
        const ushort h0 = f2bf(w2.x);
        const ushort h1 = f2bf(w2.y);
        ((uint*)Whi)[gt] = (uint)h0 | ((uint)h1 << 16);
        ((uint*)Wlo)[gt] = (uint)f2bf(w2.x - bf2f(h0)) |
                           ((uint)f2bf(w2.y - bf2f(h1)) << 16);
    }
    if (USEBF) {
        for (int i = gt; i < N * P_DIM; i += G) {
            const float2 ab = ((const float2*)pose)[i];
            pose_bf[i] = (uint)f2bf(ab.x) | ((uint)f2bf(ab.y) << 16);
        }
    }
    {
        const float4 b4 = ((const float4*)bias)[gt & 3];
        for (int i = gt; i < N * 4; i += G) ((float4*)out)[i] = b4;
    }
}

// ---------------------------------------------------------------------------
// Gemm LDS staging: pure vector copy of prepped tables, XOR-swizzled dest
// (half ^= (row&7)<<3) — applied identically on write and read.
// ---------------------------------------------------------------------------
__device__ __forceinline__ void stage_tables(int tid,
                                             const ushort* __restrict__ Whi,
                                             const ushort* __restrict__ Wlo,
                                             ushort* w_hi, ushort* w_lo) {
    for (int i = tid; i < 160 * 16; i += 256) {
        const uint4 vh = ((const uint4*)Whi)[i];
        const uint4 vl = ((const uint4*)Wlo)[i];
        const int lin = i * 8;
        const int j   = lin >> 6;
        const int w   = lin & 63;
        const int swz = j * 64 + (w ^ ((j & 7) << 3));
        *(uint4*)&w_hi[swz] = vh;
        *(uint4*)&w_lo[swz] = vl;
    }
}

// ---------------------------------------------------------------------------
// One 64-row gemm tile (r10 structure): split-bf16 3-product MFMA,
// direct padded stores (16 col-lanes -> 32B contiguous chunks).
// ---------------------------------------------------------------------------
__device__ __forceinline__ void gemm_tile(int tile, int tid,
                                          const float* __restrict__ x,
                                          ushort* __restrict__ Zb, int N,
                                          const ushort* w_hi, const ushort* w_lo) {
    const int block_row = tile * 64;
    const int lane = tid & 63;
    const int wv   = tid >> 6;
    const int col  = lane & 15;
    const int kg   = lane >> 4;

    const int arow = block_row + wv * 16 + col;
    const float* xr = x + (size_t)(arow < N ? arow : 0) * C_DIM;
    float4 x0 = ((const float4*)xr)[kg * 2];
    float4 x1 = ((const float4*)xr)[kg * 2 + 1];
    float4 x2 = ((const float4*)xr)[8 + kg * 2];
    float4 x3 = ((const float4*)xr)[8 + kg * 2 + 1];
    if (arow >= N) {
        x0 = x1 = x2 = x3 = make_float4(0.f, 0.f, 0.f, 0.f);
    }

    short8v a_hi0, a_lo0, a_hi1, a_lo1;
    {
        const float t0[8] = {x0.x, x0.y, x0.z, x0.w, x1.x, x1.y, x1.z, x1.w};
        const float t1[8] = {x2.x, x2.y, x2.z, x2.w, x3.x, x3.y, x3.z, x3.w};
        #pragma unroll
        for (int e = 0; e < 8; ++e) {
            const ushort h = f2bf(t0[e]);
            a_hi0[e] = (short)h;
            a_lo0[e] = (short)f2bf(t0[e] - bf2f(h));
            const ushort g = f2bf(t1[e]);
            a_hi1[e] = (short)g;
            a_lo1[e] = (short)f2bf(t1[e] - bf2f(g));
        }
    }

    // C/D layout (HW-verified): col = lane&15, row = kg*4 + reg
    const int orow0 = block_row + wv * 16 + kg * 4;

    #pragma unroll
    for (int nt = 0; nt < NT; ++nt) {
        const int j  = nt * 16 + col;             // padded slot (0..159)
        const int sx = (j & 7) << 3;
        const int b0off = j * 64 + ((kg * 8) ^ sx);
        const int b1off = j * 64 + ((32 + kg * 8) ^ sx);
        const short8v bh0 = *(const short8v*)&w_hi[b0off];
        const short8v bh1 = *(const short8v*)&w_hi[b1off];
        const short8v bl0 = *(const short8v*)&w_lo[b0off];
        const short8v bl1 = *(const short8v*)&w_lo[b1off];

        f32x4 acc = {0.f, 0.f, 0.f, 0.f};
        acc = __builtin_amdgcn_mfma_f32_16x16x32_bf16(a_lo0, bh0, acc, 0, 0, 0);
        acc = __builtin_amdgcn_mfma_f32_16x16x32_bf16(a_hi0, bl0, acc, 0, 0, 0);
        acc = __builtin_amdgcn_mfma_f32_16x16x32_bf16(a_lo1, bh1, acc, 0, 0, 0);
        acc = __builtin_amdgcn_mfma_f32_16x16x32_bf16(a_hi1, bl1, acc, 0, 0, 0);
        acc = __builtin_amdgcn_mfma_f32_16x16x32_bf16(a_hi0, bh0, acc, 0, 0, 0);
        acc = __builtin_amdgcn_mfma_f32_16x16x32_bf16(a_hi1, bh1, acc, 0, 0, 0);

        #pragma unroll
        for (int r = 0; r < 4; ++r) {
            const int row = orow0 + r;
            if (row < N) Zb[(size_t)row * ZNODE + j] = f2bf(acc[r]);
        }
    }
}

// ---------------------------------------------------------------------------
// One edge batch of 128 edges (r7's measured-best body, 57.4us): eager
// whole-row Zb loads (dwordx4 + dword), 2 serial miss levels, in-register
// tap select from the 6-halfword window at 3*b1.
// ---------------------------------------------------------------------------
template <bool USEBF>
__device__ __forceinline__ void edge_batch(int b, int tid,
                                           const int* __restrict__ ei,
                                           const float* __restrict__ pos,
                                           const float* __restrict__ pose,
                                           const uint* __restrict__ pose_bf,
                                           const ushort* __restrict__ Zb,
                                           float* __restrict__ out, int E) {
    const int p  = tid & 15;
    const int eg = tid >> 4;
    const int e0 = b * (16 * EILP) + eg;

    int  r[EILP], c[EILP];
    bool valid[EILP];
    #pragma unroll
    for (int it = 0; it < EILP; ++it) {
        int e = e0 + it * 16;
        valid[it] = (e < E);
        int ec = valid[it] ? e : 0;
        r[it] = ei[ec];
        c[it] = ei[E + ec];
    }

    float d0[EILP], d1[EILP];
    #pragma unroll
    for (int it = 0; it < EILP; ++it) {
        const float2 pc = ((const float2*)pos)[c[it]];
        const float2 pr = ((const float2*)pos)[r[it]];
        d0[it] = (pc.x - pr.x) * INV2S;
        d1[it] = (pc.y - pr.y) * INV2S;
    }

    float a_[EILP], b_[EILP];
    #pragma unroll
    for (int it = 0; it < EILP; ++it) {
        if (USEBF) {
            const uint ab = pose_bf[(size_t)r[it] * P_DIM + p];
            a_[it] = bf2f((ushort)(ab & 0xffffu));
            b_[it] = bf2f((ushort)(ab >> 16));
        } else {
            const float2 ab = ((const float2*)pose)[(size_t)r[it] * P_DIM + p];
            a_[it] = ab.x;
            b_[it] = ab.y;
        }
    }

    uint4a qv[EILP];
    uint   q4[EILP];
    #pragma unroll
    for (int it = 0; it < EILP; ++it) {
        const uint* Zp = (const uint*)(Zb + (size_t)c[it] * ZNODE) + p * (ZROW / 2);
        qv[it] = *(const uint4a*)Zp;
        q4[it] = Zp[4];
    }

    #pragma unroll
    for (int it = 0; it < EILP; ++it) {
        const float p0 = fmaf(a_[it], d0[it], fmaf(-b_[it], d1[it], 0.5f));
        const float p1 = fmaf(b_[it], d0[it], fmaf( a_[it], d1[it], 0.5f));

        const float v0 = fminf(fmaxf(p0, 0.0f), 1.0f) * 2.0f;
        const float v1 = fminf(fmaxf(p1, 0.0f), 1.0f) * 2.0f;
        // base: b0=(v0>=1), b1=(v1>=1); at v==2: base 1, frac 1 -> col 2,
        // matching the reference's clamped i00==i01==2 case exactly.
        const bool b0 = (v0 >= 1.0f);
        const bool b1 = (v1 >= 1.0f);
        const float f0 = v0 - (b0 ? 1.0f : 0.0f);
        const float f1 = v1 - (b1 ? 1.0f : 0.0f);

        const uint A0 = qv[it][0], A1 = qv[it][1], A2 = qv[it][2],
                   A3 = qv[it][3], A4 = q4[it];
        const uint W0 = b1 ? ((A1 >> 16) | (A2 << 16)) : A0;
        const uint W1 = b1 ? ((A2 >> 16) | (A3 << 16)) : A1;
        const uint W2 = b1 ? ((A3 >> 16) | (A4 << 16)) : A2;
        const uint s = b0 ? 16u : 0u;
        const float z00 = bf2f((ushort)(W0 >> s));
        const float z10 = bf2f((ushort)(b0 ? (W1 & 0xffffu) : (W0 >> 16)));
        const float z01 = bf2f((ushort)(b0 ? (W2 & 0xffffu) : (W1 >> 16)));
        const float z11 = bf2f((ushort)(W2 >> s));

        const float w00 = (1.0f - f0) * (1.0f - f1);
        const float w01 = (1.0f - f0) * f1;
        const float w10 = f0 * (1.0f - f1);
        const float w11 = f0 * f1;

        float m = w00 * z00;
        m = fmaf(w01, z01, m);
        m = fmaf(w10, z10, m);
        m = fmaf(w11, z11, m);

        if (valid[it]) atomicAdd(&out[(size_t)r[it] * P_DIM + p], m);
    }
}

// ---------------------------------------------------------------------------
// Fused cooperative kernel: prep -> sync -> gemm -> sync -> edge.
// Removes 3 inter-dispatch gaps (the inferred ~25us hidden cost).
// ---------------------------------------------------------------------------
template <bool USEBF>
__global__ __launch_bounds__(256, 4) void fused_kernel(const float* __restrict__ x,
                                                       const float* __restrict__ pos,
                                                       const float* __restrict__ pose,
                                                       const float* __restrict__ W,
                                                       const float* __restrict__ bias,
                                                       const int* __restrict__ ei,
                                                       float* __restrict__ out,
                                                       ushort* __restrict__ Whi,
                                                       ushort* __restrict__ Wlo,
                                                       ushort* __restrict__ Zb,
                                                       uint* __restrict__ pose_bf,
                                                       int N, int E) {
    __shared__ ushort w_hi[WELEM];   // 20480 B
    __shared__ ushort w_lo[WELEM];   // 20480 B
    cg::grid_group grid = cg::this_grid();

    const int tid = threadIdx.x;
    const int gt  = blockIdx.x * 256 + tid;
    const int G   = gridDim.x * 256;

    // phase 0: prep
    do_prep<USEBF>(gt, G, W, pose, bias, out, Whi, Wlo, pose_bf, N);
    __threadfence();
    grid.sync();

    // phase 1: gemm (grid-strided tiles)
    stage_tables(tid, Whi, Wlo, w_hi, w_lo);
    __syncthreads();
    const int ntiles = (N + 63) / 64;
    for (int t = blockIdx.x; t < ntiles; t += gridDim.x)
        gemm_tile(t, tid, x, Zb, N, w_hi, w_lo);
    __threadfence();
    grid.sync();

    // phase 2: edge (grid-strided batches)
    const int nb = (E + 16 * EILP - 1) / (16 * EILP);
    for (int b = blockIdx.x; b < nb; b += gridDim.x)
        edge_batch<USEBF>(b, tid, ei, pos, pose, pose_bf, Zb, out, E);
}

// --------------------- fallback (r10 three-dispatch path) ------------------
template <bool USEBF>
__global__ __launch_bounds__(256) void prep_kernel(const float* __restrict__ W,
                                                   const float* __restrict__ pose,
                                                   const float* __restrict__ bias,
                                                   float* __restrict__ out,
                                                   ushort* __restrict__ Whi,
                                                   ushort* __restrict__ Wlo,
                                                   uint* __restrict__ pose_bf, int N) {
    do_prep<USEBF>(blockIdx.x * 256 + threadIdx.x, gridDim.x * 256,
                   W, pose, bias, out, Whi, Wlo, pose_bf, N);
}

__global__ __launch_bounds__(256) void z_gemm_kernel(const float* __restrict__ x,
                                                     const ushort* __restrict__ Whi,
                                                     const ushort* __restrict__ Wlo,
                                                     ushort* __restrict__ Zb, int N) {
    __shared__ ushort w_hi[WELEM];
    __shared__ ushort w_lo[WELEM];
    stage_tables(threadIdx.x, Whi, Wlo, w_hi, w_lo);
    __syncthreads();
    gemm_tile(blockIdx.x, threadIdx.x, x, Zb, N, w_hi, w_lo);
}

template <bool USEBF>
__global__ __launch_bounds__(256) void edge_kernel(const int* __restrict__ ei,
                                                   const float* __restrict__ pos,
                                                   const float* __restrict__ pose,
                                                   const uint* __restrict__ pose_bf,
                                                   const ushort* __restrict__ Zb,
                                                   float* __restrict__ out, int E) {
    edge_batch<USEBF>(blockIdx.x, threadIdx.x, ei, pos, pose, pose_bf, Zb, out, E);
}

// ---------------------------------------------------------------------------
extern "C" void kernel_launch(void* const* d_in, const int* in_sizes, int n_in,
                              void* d_out, int out_size, void* d_ws, size_t ws_size,
                              hipStream_t stream) {
    const float* x    = (const float*)d_in[0];
    const float* pos  = (const float*)d_in[1];
    const float* pose = (const float*)d_in[2];
    const float* W    = (const float*)d_in[3];
    const float* bias = (const float*)d_in[4];
    const int*   ei   = (const int*)d_in[5];

    const int N = in_sizes[0] / C_DIM;   // 50000
    const int E = in_sizes[5] / 2;       // 800000

    float* out = (float*)d_out;

    // workspace layout: [Whi 20KB][Wlo 20KB][Zb 16MB][pose_bf 3.2MB gated]
    ushort* Whi = (ushort*)d_ws;
    ushort* Wlo = Whi + WELEM;
    ushort* Zb  = Wlo + WELEM;

    const size_t w_bytes    = (size_t)2 * WELEM * sizeof(ushort);
    const size_t zb_bytes   = (size_t)N * ZNODE * sizeof(ushort);
    const size_t pose_bytes = (size_t)N * P_DIM * sizeof(uint);
    uint* pose_bf = (ws_size >= w_bytes + zb_bytes + pose_bytes)
                        ? (uint*)((char*)Zb + zb_bytes) : nullptr;

    // --- try the fused cooperative launch (1024 -> 512), else fall back ---
    void* args[] = {(void*)&x, (void*)&pos, (void*)&pose, (void*)&W,
                    (void*)&bias, (void*)&ei, (void*)&out, (void*)&Whi,
                    (void*)&Wlo, (void*)&Zb, (void*)&pose_bf,
                    (void*)&N, (void*)&E};
    const void* fk = (pose_bf != nullptr)
                         ? (const void*)&fused_kernel<true>
                         : (const void*)&fused_kernel<false>;
    hipError_t err = hipLaunchCooperativeKernel(fk, dim3(1024), dim3(256),
                                                args, 0, stream);
    if (err != hipSuccess)
        err = hipLaunchCooperativeKernel(fk, dim3(512), dim3(256),
                                         args, 0, stream);
    if (err == hipSuccess) return;

    // fallback: r10's three-dispatch path
    if (pose_bf != nullptr)
        prep_kernel<true><<<3200, 256, 0, stream>>>(W, pose, bias, out, Whi, Wlo, pose_bf, N);
    else
        prep_kernel<false><<<3200, 256, 0, stream>>>(W, pose, bias, out, Whi, Wlo, pose_bf, N);
    z_gemm_kernel<<<(N + 63) / 64, 256, 0, stream>>>(x, Whi, Wlo, Zb, N);
    const int eblocks = (E + 16 * EILP - 1) / (16 * EILP);
    if (pose_bf != nullptr)
        edge_kernel<true><<<eblocks, 256, 0, stream>>>(ei, pos, pose, pose_bf, Zb, out, E);
    else
        edge_kernel<false><<<eblocks, 256, 0, stream>>>(ei, pos, pose, pose_bf, Zb, out, E);
}

// Round 12
// 147.945 us; speedup vs baseline: 3.8103x; 3.8103x over previous
//
#include <hip/hip_runtime.h>

// Problem constants (fixed by the reference's setup_inputs)
#define C_DIM 64
#define P_DIM 16
#define K_DIM 9
#define ZROW 10              // padded Zb row (ushorts) per (n,p): 20 B
#define ZNODE (P_DIM * ZROW) // 160 ushorts = 320 B per node
#define NT 10                // n-tiles (permuted 160-slot output layout)
#define WELEM (160 * C_DIM)  // ushorts per W' table (10240)
#define INV2S 0.35355339059327373f  // 1/(2*sqrt(2))

typedef __attribute__((ext_vector_type(8))) short short8v;  // 8 bf16 (4 VGPRs)
typedef __attribute__((ext_vector_type(4))) float f32x4;    // MFMA accumulator
typedef uint uint4a __attribute__((ext_vector_type(4), aligned(4)));

__device__ __forceinline__ ushort f2bf(float f) {
    uint u = __builtin_bit_cast(uint, f);
    return (ushort)((u + 0x7FFFu + ((u >> 16) & 1u)) >> 16);   // RNE
}
__device__ __forceinline__ float bf2f(ushort h) {
    return __builtin_bit_cast(float, ((uint)h) << 16);
}

// ---------------------------------------------------------------------------
// Kernel 0 (prep, one-shot): (a) permuted W' -> global bf16 hi/lo tables
// (row j holds W[(j/10)*9 + j%10], zeros at j%10==9), (b) pose -> packed
// bf16 table, (c) bias-init of out.
// ---------------------------------------------------------------------------
__global__ __launch_bounds__(256) void prep_kernel(const float* __restrict__ W,
                                                   const float* __restrict__ pose,
                                                   const float* __restrict__ bias,
                                                   float* __restrict__ out,
                                                   ushort* __restrict__ Whi,
                                                   ushort* __restrict__ Wlo,
                                                   uint* __restrict__ pose_bf,
                                                   int N) {
    const int g = blockIdx.x * 256 + threadIdx.x;
    const int gsz = gridDim.x * 256;

    // (a) W' tables: 5120 dwords per table
    if (g < WELEM / 2) {
        const int j  = g >> 5;           // W' row (0..159)
        const int k2 = g & 31;           // float2 index within row
        const int p  = j / 10;
        const int k  = j - p * 10;
        float2 w2 = make_float2(0.0f, 0.0f);
        if (k < 9) w2 = ((const float2*)W)[(p * 9 + k) * (C_DIM / 2) + k2];
        const ushort h0 = f2bf(w2.x);
        const ushort h1 = f2bf(w2.y);
        ((uint*)Whi)[g] = (uint)h0 | ((uint)h1 << 16);
        ((uint*)Wlo)[g] = (uint)f2bf(w2.x - bf2f(h0)) |
                          ((uint)f2bf(w2.y - bf2f(h1)) << 16);
    }

    // (b) pose -> packed bf16 (measured -3us on edge, r4 vs r5)
    if (pose_bf != nullptr) {
        for (int i = g; i < N * P_DIM; i += gsz) {
            const float2 ab = ((const float2*)pose)[i];
            pose_bf[i] = (uint)f2bf(ab.x) | ((uint)f2bf(ab.y) << 16);
        }
    }

    // (c) bias-init out: N*4 float4s
    {
        const float4 b4 = ((const float4*)bias)[g & 3];
        for (int i = g; i < N * 4; i += gsz) ((float4*)out)[i] = b4;
    }
}

// ---------------------------------------------------------------------------
// Kernel 1 (MFMA): Zb[n][s] (s = p*10+k, padded) = sum_c x[n,c]*W[p,k,c]
// via split-bf16 3-product MFMA. 64 rows/block, 4 waves.
// Staging = pure vector copy of the prepped tables, XOR-swizzled LDS
// (half ^= (row&7)<<3) applied identically on write and read.
// ---------------------------------------------------------------------------
__global__ __launch_bounds__(256) void z_gemm_kernel(const float* __restrict__ x,
                                                     const ushort* __restrict__ Whi,
                                                     const ushort* __restrict__ Wlo,
                                                     ushort* __restrict__ Zb,
                                                     int N) {
    __shared__ ushort w_hi[WELEM];   // 20480 B
    __shared__ ushort w_lo[WELEM];   // 20480 B

    const int tid = threadIdx.x;
    const int block_row = blockIdx.x * 64;

    // stage both tables: 160*16 uint4s each, swizzled LDS dest
    for (int i = tid; i < 160 * 16; i += 256) {
        const uint4 vh = ((const uint4*)Whi)[i];
        const uint4 vl = ((const uint4*)Wlo)[i];
        const int lin = i * 8;                    // half-offset (mult of 8)
        const int j   = lin >> 6;                 // row
        const int w   = lin & 63;
        const int swz = j * 64 + (w ^ ((j & 7) << 3));
        *(uint4*)&w_hi[swz] = vh;
        *(uint4*)&w_lo[swz] = vl;
    }
    __syncthreads();

    const int lane = tid & 63;
    const int wv   = tid >> 6;    // wave -> m-subtile (16 rows)
    const int col  = lane & 15;   // A row within tile / B,C/D column
    const int kg   = lane >> 4;   // k-group 0..3

    // A operand: lane supplies x[arow][kg*8 + e (+32*chunk)], split hi/lo.
    const int arow = block_row + wv * 16 + col;
    const float* xr = x + (size_t)(arow < N ? arow : 0) * C_DIM;
    float4 x0 = ((const float4*)xr)[kg * 2];
    float4 x1 = ((const float4*)xr)[kg * 2 + 1];
    float4 x2 = ((const float4*)xr)[8 + kg * 2];
    float4 x3 = ((const float4*)xr)[8 + kg * 2 + 1];
    if (arow >= N) {
        x0 = x1 = x2 = x3 = make_float4(0.f, 0.f, 0.f, 0.f);
    }

    short8v a_hi0, a_lo0, a_hi1, a_lo1;
    {
        const float t0[8] = {x0.x, x0.y, x0.z, x0.w, x1.x, x1.y, x1.z, x1.w};
        const float t1[8] = {x2.x, x2.y, x2.z, x2.w, x3.x, x3.y, x3.z, x3.w};
        #pragma unroll
        for (int e = 0; e < 8; ++e) {
            const ushort h = f2bf(t0[e]);
            a_hi0[e] = (short)h;
            a_lo0[e] = (short)f2bf(t0[e] - bf2f(h));
            const ushort g = f2bf(t1[e]);
            a_hi1[e] = (short)g;
            a_lo1[e] = (short)f2bf(t1[e] - bf2f(g));
        }
    }

    // C/D layout (HW-verified): col = lane&15, row = kg*4 + reg
    const int orow0 = block_row + wv * 16 + kg * 4;

    #pragma unroll
    for (int nt = 0; nt < NT; ++nt) {
        const int j  = nt * 16 + col;             // padded slot (0..159)
        const int sx = (j & 7) << 3;              // row swizzle
        const int b0off = j * 64 + ((kg * 8) ^ sx);
        const int b1off = j * 64 + ((32 + kg * 8) ^ sx);
        const short8v bh0 = *(const short8v*)&w_hi[b0off];
        const short8v bh1 = *(const short8v*)&w_hi[b1off];
        const short8v bl0 = *(const short8v*)&w_lo[b0off];
        const short8v bl1 = *(const short8v*)&w_lo[b1off];

        f32x4 acc = {0.f, 0.f, 0.f, 0.f};
        // split-bf16 3-product: lo terms first, hi*hi last
        acc = __builtin_amdgcn_mfma_f32_16x16x32_bf16(a_lo0, bh0, acc, 0, 0, 0);
        acc = __builtin_amdgcn_mfma_f32_16x16x32_bf16(a_hi0, bl0, acc, 0, 0, 0);
        acc = __builtin_amdgcn_mfma_f32_16x16x32_bf16(a_lo1, bh1, acc, 0, 0, 0);
        acc = __builtin_amdgcn_mfma_f32_16x16x32_bf16(a_hi1, bl1, acc, 0, 0, 0);
        acc = __builtin_amdgcn_mfma_f32_16x16x32_bf16(a_hi0, bh0, acc, 0, 0, 0);
        acc = __builtin_amdgcn_mfma_f32_16x16x32_bf16(a_hi1, bh1, acc, 0, 0, 0);

        // direct store: slot == j; 16 col-lanes -> 32B contiguous chunks
        #pragma unroll
        for (int r = 0; r < 4; ++r) {
            const int row = orow0 + r;
            if (row < N) Zb[(size_t)row * ZNODE + j] = f2bf(acc[r]);
        }
    }
}

// ---------------------------------------------------------------------------
// Kernel 2: edge messages + scatter-add (unsorted), r7/r10 structure with
// EILP 8 -> 12: +50% independent gather streams per wave (latency-bound,
// realized occupancy 37% means the VGPR-cap drop 8->6 waves/SIMD is free).
// Eager whole-row Zb loads (dwordx4 + dword) keep the gather chain at
// 2 serial miss levels; 4 spline taps selected in-register.
// ---------------------------------------------------------------------------
#define EILP 12
template <bool USEBF>
__global__ __launch_bounds__(256) void edge_kernel(const int* __restrict__ ei,
                                                   const float* __restrict__ pos,
                                                   const float* __restrict__ pose,
                                                   const uint* __restrict__ pose_bf,
                                                   const ushort* __restrict__ Zb,
                                                   float* __restrict__ out,
                                                   int E) {
    const int p  = threadIdx.x & 15;
    const int eg = threadIdx.x >> 4;
    const int e0 = blockIdx.x * (16 * EILP) + eg;

    int  r[EILP], c[EILP];
    bool valid[EILP];
    #pragma unroll
    for (int it = 0; it < EILP; ++it) {
        int e = e0 + it * 16;
        valid[it] = (e < E);
        int ec = valid[it] ? e : 0;
        r[it] = ei[ec];
        c[it] = ei[E + ec];
    }

    // --- eager independent gathers: pos, pose, and the full Zb row ---
    float d0[EILP], d1[EILP];
    #pragma unroll
    for (int it = 0; it < EILP; ++it) {
        const float2 pc = ((const float2*)pos)[c[it]];
        const float2 pr = ((const float2*)pos)[r[it]];
        d0[it] = (pc.x - pr.x) * INV2S;
        d1[it] = (pc.y - pr.y) * INV2S;
    }

    float a_[EILP], b_[EILP];
    #pragma unroll
    for (int it = 0; it < EILP; ++it) {
        if (USEBF) {
            const uint ab = pose_bf[(size_t)r[it] * P_DIM + p];
            a_[it] = bf2f((ushort)(ab & 0xffffu));
            b_[it] = bf2f((ushort)(ab >> 16));
        } else {
            const float2 ab = ((const float2*)pose)[(size_t)r[it] * P_DIM + p];
            a_[it] = ab.x;
            b_[it] = ab.y;
        }
    }

    uint4a qv[EILP];
    uint   q4[EILP];
    #pragma unroll
    for (int it = 0; it < EILP; ++it) {
        const uint* Zp = (const uint*)(Zb + (size_t)c[it] * ZNODE) + p * (ZROW / 2);
        qv[it] = *(const uint4a*)Zp;   // dwordx4 (4B-aligned ok on gfx9+)
        q4[it] = Zp[4];
    }

    #pragma unroll
    for (int it = 0; it < EILP; ++it) {
        const float p0 = fmaf(a_[it], d0[it], fmaf(-b_[it], d1[it], 0.5f));
        const float p1 = fmaf(b_[it], d0[it], fmaf( a_[it], d1[it], 0.5f));

        const float v0 = fminf(fmaxf(p0, 0.0f), 1.0f) * 2.0f;
        const float v1 = fminf(fmaxf(p1, 0.0f), 1.0f) * 2.0f;
        // window base: b0 = (v0>=1), b1 = (v1>=1); fracs relative to base.
        // (at v==2: base 1, frac 1 -> weight on column 2; matches the
        //  reference's clamped i00==i01==2 case exactly)
        const bool b0 = (v0 >= 1.0f);
        const bool b1 = (v1 >= 1.0f);
        const float f0 = v0 - (b0 ? 1.0f : 0.0f);
        const float f1 = v1 - (b1 ? 1.0f : 0.0f);

        // 6-element window w0..w5 = e(3*b1) .. e(3*b1+5) as 3 dwords
        const uint A0 = qv[it][0], A1 = qv[it][1], A2 = qv[it][2],
                   A3 = qv[it][3], A4 = q4[it];
        const uint W0 = b1 ? ((A1 >> 16) | (A2 << 16)) : A0;
        const uint W1 = b1 ? ((A2 >> 16) | (A3 << 16)) : A1;
        const uint W2 = b1 ? ((A3 >> 16) | (A4 << 16)) : A2;
        // taps: z00=w(b0), z10=w(b0+1), z01=w(b0+3), z11=w(b0+4)
        const uint s = b0 ? 16u : 0u;
        const float z00 = bf2f((ushort)(W0 >> s));
        const float z10 = bf2f((ushort)(b0 ? (W1 & 0xffffu) : (W0 >> 16)));
        const float z01 = bf2f((ushort)(b0 ? (W2 & 0xffffu) : (W1 >> 16)));
        const float z11 = bf2f((ushort)(W2 >> s));

        const float w00 = (1.0f - f0) * (1.0f - f1);
        const float w01 = (1.0f - f0) * f1;
        const float w10 = f0 * (1.0f - f1);
        const float w11 = f0 * f1;

        float m = w00 * z00;
        m = fmaf(w01, z01, m);
        m = fmaf(w10, z10, m);
        m = fmaf(w11, z11, m);

        if (valid[it]) atomicAdd(&out[(size_t)r[it] * P_DIM + p], m);
    }
}

// ---------------------------------------------------------------------------
extern "C" void kernel_launch(void* const* d_in, const int* in_sizes, int n_in,
                              void* d_out, int out_size, void* d_ws, size_t ws_size,
                              hipStream_t stream) {
    const float* x    = (const float*)d_in[0];
    const float* pos  = (const float*)d_in[1];
    const float* pose = (const float*)d_in[2];
    const float* W    = (const float*)d_in[3];
    const float* bias = (const float*)d_in[4];
    const int*   ei   = (const int*)d_in[5];

    const int N = in_sizes[0] / C_DIM;   // 50000
    const int E = in_sizes[5] / 2;       // 800000

    float* out = (float*)d_out;

    // workspace layout: [Whi 20KB][Wlo 20KB][Zb 16MB][pose_bf 3.2MB gated]
    ushort* Whi = (ushort*)d_ws;
    ushort* Wlo = Whi + WELEM;
    ushort* Zb  = Wlo + WELEM;

    const size_t w_bytes    = (size_t)2 * WELEM * sizeof(ushort);
    const size_t zb_bytes   = (size_t)N * ZNODE * sizeof(ushort);
    const size_t pose_bytes = (size_t)N * P_DIM * sizeof(uint);
    uint* pose_bf = (ws_size >= w_bytes + zb_bytes + pose_bytes)
                        ? (uint*)((char*)Zb + zb_bytes) : nullptr;

    prep_kernel<<<3200, 256, 0, stream>>>(W, pose, bias, out, Whi, Wlo, pose_bf, N);
    z_gemm_kernel<<<(N + 63) / 64, 256, 0, stream>>>(x, Whi, Wlo, Zb, N);

    const int eblocks = (E + 16 * EILP - 1) / (16 * EILP);
    if (pose_bf != nullptr)
        edge_kernel<true><<<eblocks, 256, 0, stream>>>(ei, pos, pose, pose_bf, Zb, out, E);
    else
        edge_kernel<false><<<eblocks, 256, 0, stream>>>(ei, pos, pose, pose_bf, Zb, out, E);
}